// Round 12
// baseline (419.204 us; speedup 1.0000x reference)
//
#include <hip/hip_runtime.h>

typedef unsigned short ushort_t;
typedef float f32x4 __attribute__((ext_vector_type(4)));
typedef _Float16 f16x8 __attribute__((ext_vector_type(8)));
typedef short s16x8 __attribute__((ext_vector_type(8)));

#define NB 8
#define QL 256
#define HID 4096
#define NH 32
#define HD 128

__device__ __forceinline__ _Float16 f2h(float f) { return (_Float16)f; }
__device__ __forceinline__ ushort_t h2u(_Float16 h) {
  union { _Float16 h; ushort_t u; } x; x.h = h; return x.u;
}
__device__ __forceinline__ float u2f(ushort_t u) {
  union { _Float16 h; ushort_t u; } x; x.u = u; return (float)x.h;
}

#define MFMA16H(a, b, c) __builtin_amdgcn_mfma_f32_16x16x32_f16((a), (b), (c), 0, 0, 0)
#define AS1 __attribute__((address_space(1)))
#define AS3 __attribute__((address_space(3)))
#define VMCNT(n) asm volatile("s_waitcnt vmcnt(" #n ")" ::: "memory")
#define NOSTG

#define GLDS(srcp, dstofs)                                                    \
  __builtin_amdgcn_global_load_lds((const AS1 void*)(srcp),                   \
                                   (AS3 void*)&lds[dstofs], 16, 0, 0)

// ---------------------------------------------------------------------------
// fp32 -> fp16, MFMA-native tiling: dst[mb][kb][lane][8],
// lane = (row&15) | (seg<<4), element = src[mb*16+row][kb*32+seg*8+j].
// ---------------------------------------------------------------------------
__global__ __launch_bounds__(256)
void conv_tile(const float* __restrict__ src, ushort_t* __restrict__ dst,
               int K, int ntiles) {
  const int tile = blockIdx.x * 4 + (threadIdx.x >> 6);
  if (tile >= ntiles) return;
  const int u = threadIdx.x & 63;
  const int row = u >> 2, seg = u & 3;
  const int K32 = K >> 5;
  const int mb = tile / K32, kb = tile % K32;
  const float* sp = src + (size_t)(mb * 16 + row) * K + kb * 32 + seg * 8;
  ushort_t t[8];
#pragma unroll
  for (int j = 0; j < 8; ++j) t[j] = h2u(f2h(sp[j]));
  *(s16x8*)(dst + (size_t)tile * 512 + (((seg << 4) | row) * 8)) = *(s16x8*)t;
}

// ---------------------------------------------------------------------------
// qkv GEMM (measured-best: 180us, MfmaUtil 58%, 0 conflicts):
// BM=256 BN=128 BK=32, 8 waves (4Mx2N, wave 64x64), ring-3 LDS 72KB
// (2 blocks/CU), 1 barrier + counted vmcnt(3) per K-tile, tiled operands.
// ---------------------------------------------------------------------------
template<int NT>
__global__ __launch_bounds__(512, 4)
void gemm_qkv(const ushort_t* __restrict__ At, const ushort_t* __restrict__ Bt,
              const float* __restrict__ bias, ushort_t* __restrict__ Ch,
              int N) {
  static_assert(NT % 3 == 2 && NT >= 8, "tail assumes NT%3==2");
  extern __shared__ ushort_t lds[];  // 3 rings x (A 8192 + B 4096) elems
  const int nwg = gridDim.x, bid = blockIdx.x;
  const int wg = (bid & 7) * (nwg >> 3) + (bid >> 3);  // XCD-bijective
  const int mi = wg & 7, ni = wg >> 3;
  const int tid = threadIdx.x, w = tid >> 6, l = tid & 63;
  const int l16 = l & 15, lg = l >> 4;
  const int wm = w >> 1, wn = w & 1;

  const ushort_t* sA0 = At + ((size_t)(mi * 16 + 2 * w) * NT) * 512 + l * 8;
  const ushort_t* sA1 = At + ((size_t)(mi * 16 + 2 * w + 1) * NT) * 512 + l * 8;
  const ushort_t* sB  = Bt + ((size_t)(ni * 8 + w) * NT) * 512 + l * 8;

  int aof[4], bof[4];
#pragma unroll
  for (int mf = 0; mf < 4; ++mf) aof[mf] = (wm * 4 + mf) * 512 + l * 8;
#pragma unroll
  for (int nf = 0; nf < 4; ++nf) bof[nf] = 8192 + (wn * 4 + nf) * 512 + l * 8;

  f32x4 acc[4][4];
#pragma unroll
  for (int m = 0; m < 4; ++m)
#pragma unroll
    for (int n = 0; n < 4; ++n) acc[m][n] = (f32x4){0.f, 0.f, 0.f, 0.f};

#define STGQ(R, J)                                                            \
  do {                                                                        \
    GLDS(sA0 + (size_t)(J) * 512, (R) * 12288 + (2 * w) * 512);               \
    GLDS(sA1 + (size_t)(J) * 512, (R) * 12288 + (2 * w + 1) * 512);           \
    GLDS(sB + (size_t)(J) * 512, (R) * 12288 + 8192 + w * 512);               \
  } while (0)

#define ITERQ(R, VMW, STGCODE)                                                \
  do {                                                                        \
    VMW;                                                                      \
    __builtin_amdgcn_s_barrier();                                             \
    STGCODE;                                                                  \
    f16x8 fa[4], fb[4];                                                       \
    _Pragma("unroll") for (int mf = 0; mf < 4; ++mf)                          \
        fa[mf] = *(const f16x8*)&lds[(R) * 12288 + aof[mf]];                  \
    _Pragma("unroll") for (int nf = 0; nf < 4; ++nf)                          \
        fb[nf] = *(const f16x8*)&lds[(R) * 12288 + bof[nf]];                  \
    asm volatile("s_waitcnt lgkmcnt(0)" ::: "memory");                        \
    __builtin_amdgcn_sched_barrier(0);                                        \
    __builtin_amdgcn_s_setprio(1);                                            \
    _Pragma("unroll") for (int mf = 0; mf < 4; ++mf)                          \
    _Pragma("unroll") for (int nf = 0; nf < 4; ++nf)                          \
        acc[mf][nf] = MFMA16H(fa[mf], fb[nf], acc[mf][nf]);                   \
    __builtin_amdgcn_s_setprio(0);                                            \
  } while (0)

  STGQ(0, 0);
  STGQ(1, 1);
  for (int j = 0; j < NT - 2; j += 3) {
    ITERQ(0, VMCNT(3), STGQ(2, j + 2));
    ITERQ(1, VMCNT(3), STGQ(0, j + 3));
    ITERQ(2, VMCNT(3), STGQ(1, j + 4));
  }
  ITERQ(0, VMCNT(3), NOSTG);  // tile NT-2
  ITERQ(1, VMCNT(0), NOSTG);  // tile NT-1

  // epilogue: C/D layout col=l16, row=lg*4+rr
#pragma unroll
  for (int nf = 0; nf < 4; ++nf) {
    const int col = ni * 128 + wn * 64 + nf * 16 + l16;
    const float bi = bias[col];
#pragma unroll
    for (int mf = 0; mf < 4; ++mf) {
      const int row0 = mi * 256 + wm * 64 + mf * 16 + lg * 4;
#pragma unroll
      for (int rr = 0; rr < 4; ++rr)
        Ch[(size_t)(row0 + rr) * N + col] = h2u(f2h(acc[mf][nf][rr] + bi));
    }
  }
#undef STGQ
#undef ITERQ
}

// ---------------------------------------------------------------------------
// proj GEMM (measured-best for 2048x4096x4096): BM=BN=128, 4 waves
// (2Mx2N, wave 64x64), ring-3 LDS 48KB (3 blocks/CU), counted vmcnt(4),
// fp32 out. 512 blocks = exact fill.
// ---------------------------------------------------------------------------
template<int NT>
__global__ __launch_bounds__(256, 3)
void gemm_proj(const ushort_t* __restrict__ At, const ushort_t* __restrict__ Bt,
               float* __restrict__ Cf, int N) {
  static_assert(NT % 3 == 2 && NT >= 8, "tail assumes NT%3==2");
  extern __shared__ ushort_t lds[];  // 3 x (A 4096 + B 4096) elems = 48KB
  const int nwg = gridDim.x, bid = blockIdx.x;
  const int wg = (bid & 7) * (nwg >> 3) + (bid >> 3);
  const int mi = wg & 15, ni = wg >> 4;
  const int tid = threadIdx.x, w = tid >> 6, l = tid & 63;
  const int l16 = l & 15, lg = l >> 4;
  const int wm = w >> 1, wn = w & 1;

  const ushort_t* sA0 = At + ((size_t)(mi * 8 + 2 * w) * NT) * 512 + l * 8;
  const ushort_t* sA1 = At + ((size_t)(mi * 8 + 2 * w + 1) * NT) * 512 + l * 8;
  const ushort_t* sB0 = Bt + ((size_t)(ni * 8 + 2 * w) * NT) * 512 + l * 8;
  const ushort_t* sB1 = Bt + ((size_t)(ni * 8 + 2 * w + 1) * NT) * 512 + l * 8;

  int aof[4], bof[4];
#pragma unroll
  for (int mf = 0; mf < 4; ++mf) aof[mf] = (wm * 4 + mf) * 512 + l * 8;
#pragma unroll
  for (int nf = 0; nf < 4; ++nf) bof[nf] = 4096 + (wn * 4 + nf) * 512 + l * 8;

  f32x4 acc[4][4];
#pragma unroll
  for (int m = 0; m < 4; ++m)
#pragma unroll
    for (int n = 0; n < 4; ++n) acc[m][n] = (f32x4){0.f, 0.f, 0.f, 0.f};

#define STGP(R, J)                                                            \
  do {                                                                        \
    GLDS(sA0 + (size_t)(J) * 512, (R) * 8192 + (2 * w) * 512);                \
    GLDS(sA1 + (size_t)(J) * 512, (R) * 8192 + (2 * w + 1) * 512);            \
    GLDS(sB0 + (size_t)(J) * 512, (R) * 8192 + 4096 + (2 * w) * 512);         \
    GLDS(sB1 + (size_t)(J) * 512, (R) * 8192 + 4096 + (2 * w + 1) * 512);     \
  } while (0)

#define ITERP(R, VMW, STGCODE)                                                \
  do {                                                                        \
    VMW;                                                                      \
    __builtin_amdgcn_s_barrier();                                             \
    STGCODE;                                                                  \
    f16x8 fa[4], fb[4];                                                       \
    _Pragma("unroll") for (int mf = 0; mf < 4; ++mf)                          \
        fa[mf] = *(const f16x8*)&lds[(R) * 8192 + aof[mf]];                   \
    _Pragma("unroll") for (int nf = 0; nf < 4; ++nf)                          \
        fb[nf] = *(const f16x8*)&lds[(R) * 8192 + bof[nf]];                   \
    asm volatile("s_waitcnt lgkmcnt(0)" ::: "memory");                        \
    __builtin_amdgcn_sched_barrier(0);                                        \
    __builtin_amdgcn_s_setprio(1);                                            \
    _Pragma("unroll") for (int mf = 0; mf < 4; ++mf)                          \
    _Pragma("unroll") for (int nf = 0; nf < 4; ++nf)                          \
        acc[mf][nf] = MFMA16H(fa[mf], fb[nf], acc[mf][nf]);                   \
    __builtin_amdgcn_s_setprio(0);                                            \
  } while (0)

  STGP(0, 0);
  STGP(1, 1);
  for (int j = 0; j < NT - 2; j += 3) {
    ITERP(0, VMCNT(4), STGP(2, j + 2));
    ITERP(1, VMCNT(4), STGP(0, j + 3));
    ITERP(2, VMCNT(4), STGP(1, j + 4));
  }
  ITERP(0, VMCNT(4), NOSTG);
  ITERP(1, VMCNT(0), NOSTG);

#pragma unroll
  for (int nf = 0; nf < 4; ++nf) {
    const int col = ni * 128 + wn * 64 + nf * 16 + l16;
#pragma unroll
    for (int mf = 0; mf < 4; ++mf) {
      const int row0 = mi * 128 + wm * 64 + mf * 16 + lg * 4;
#pragma unroll
      for (int rr = 0; rr < 4; ++rr)
        Cf[(size_t)(row0 + rr) * N + col] = acc[mf][nf][rr];
    }
  }
#undef STGP
#undef ITERP
}

// ---------------------------------------------------------------------------
// RoPE in place on qkv (q cols 0..4095 with 1/sqrt(HD) folded; k cols
// 4096..8191; v untouched). Safe under graph replay: GEMM regenerates qkv.
// ---------------------------------------------------------------------------
__global__ __launch_bounds__(256)
void rope_inplace(ushort_t* __restrict__ qkv, const int* __restrict__ hist) {
  const int t = blockIdx.x;
  const int b = t >> 8, qq = t & 255;
  __shared__ float cs[64], sn[64];
  const int tid = threadIdx.x;
  if (tid < 64) {
    const float pos = (float)(hist[b] + qq);
    const float f = pos * __expf(-(float)tid * (9.210340371976184f / 64.0f));
    cs[tid] = cosf(f);
    sn[tid] = sinf(f);
  }
  __syncthreads();
  ushort_t* row = qkv + (size_t)t * 12288;
  const int h = tid >> 3;
  const int j0 = (tid & 7) * 8;
  const float qscale = 0.08838834764831845f;
  float c[8], s[8];
#pragma unroll
  for (int j = 0; j < 8; ++j) { c[j] = cs[j0 + j]; s[j] = sn[j0 + j]; }
  {
    ushort_t* p1 = row + h * HD + j0;
    ushort_t* p2 = p1 + 64;
    s16x8 a = *(s16x8*)p1, bb = *(s16x8*)p2;
    ushort_t o1[8], o2[8];
#pragma unroll
    for (int j = 0; j < 8; ++j) {
      const float x1 = u2f((ushort_t)a[j]), x2 = u2f((ushort_t)bb[j]);
      o1[j] = h2u(f2h((x1 * c[j] - x2 * s[j]) * qscale));
      o2[j] = h2u(f2h((x2 * c[j] + x1 * s[j]) * qscale));
    }
    *(s16x8*)p1 = *(s16x8*)o1;
    *(s16x8*)p2 = *(s16x8*)o2;
  }
  {
    ushort_t* p1 = row + HID + h * HD + j0;
    ushort_t* p2 = p1 + 64;
    s16x8 a = *(s16x8*)p1, bb = *(s16x8*)p2;
    ushort_t o1[8], o2[8];
#pragma unroll
    for (int j = 0; j < 8; ++j) {
      const float x1 = u2f((ushort_t)a[j]), x2 = u2f((ushort_t)bb[j]);
      o1[j] = h2u(f2h(x1 * c[j] - x2 * s[j]));
      o2[j] = h2u(f2h(x2 * c[j] + x1 * s[j]));
    }
    *(s16x8*)p1 = *(s16x8*)o1;
    *(s16x8*)p2 = *(s16x8*)o2;
  }
}

// ---------------------------------------------------------------------------
// Flash attention over paged KV, split over Q-halves: 512 blocks =
// (b, h, qhalf), 8 waves x 16 Q-rows each. 2 blocks/CU exact fill;
// qh=0 blocks skip causally-dead tiles (~25% work cut); co-resident blocks
// average the hist imbalance. K/V staged redundantly per half (L2-absorbed).
// Output written directly in MFMA-tiled layout (attn_t).
// ---------------------------------------------------------------------------
__global__ __launch_bounds__(512, 2)
void attn_fwd(const ushort_t* __restrict__ qkv,
              const float* __restrict__ k_cache, const float* __restrict__ v_cache,
              const int* __restrict__ hist, const int* __restrict__ bofs,
              ushort_t* __restrict__ attn_t) {
  const int bid = blockIdx.x;
  const int qh = bid & 1, bh = bid >> 1;
  const int b = bh >> 5, h = bh & 31;
  const int hb = hist[b];

  __shared__ ushort_t K_lds[64 * 136];
  __shared__ ushort_t V_lds[128 * 72];
  __shared__ ushort_t P_lds[128 * 72];

  const int tid = threadIdx.x;
  const int w = tid >> 6, l = tid & 63;
  const int l16 = l & 15, lg = l >> 4;

  // Q fragments: wave w owns rows qh*128 + w*16 + l16
  f16x8 qf[4];
  {
    const int qrow = qh * 128 + w * 16 + l16;
    const ushort_t* qp = qkv + (size_t)(b * QL + qrow) * 12288 + h * HD + lg * 8;
#pragma unroll
    for (int kd = 0; kd < 4; ++kd) qf[kd] = *(const f16x8*)(qp + kd * 32);
  }

  f32x4 o[8];
  float mr[4], sr[4];
#pragma unroll
  for (int d = 0; d < 8; ++d) o[d] = (f32x4){0.f, 0.f, 0.f, 0.f};
#pragma unroll
  for (int r = 0; r < 4; ++r) { mr[r] = -1e30f; sr[r] = 0.f; }

  // this half's tile count: max q-row = hb + qh*128 + 127
  const int nt = (hb + qh * 128 + 128 + 63) >> 6;
  const int srow = tid >> 4;
  const int seg = tid & 15;

  for (int t = 0; t < nt; ++t) {
    const int kv0 = t << 6;
    __syncthreads();
#pragma unroll
    for (int p = 0; p < 2; ++p) {
      const int row = p * 32 + srow;
      const int kvg = kv0 + row;
      if (kvg < hb) {
        const int blk = bofs[b * 12 + t];
        const size_t base = ((size_t)blk * 64 + (kvg & 63)) * HID + h * HD;
        const float* kf = k_cache + base;
        const float* vf = v_cache + base;
        ushort_t tmp[8];
#pragma unroll
        for (int j = 0; j < 8; ++j) tmp[j] = h2u(f2h(kf[seg * 8 + j]));
        *(s16x8*)&K_lds[row * 136 + seg * 8] = *(s16x8*)tmp;
#pragma unroll
        for (int j = 0; j < 8; ++j) {
          const int d = seg + j * 16;
          V_lds[d * 72 + row] = h2u(f2h(vf[d]));
        }
      } else {
        int r2 = kvg - hb;
        if (r2 > QL - 1) r2 = QL - 1;
        const size_t base = (size_t)(b * QL + r2) * 12288 + h * HD;
        const ushort_t* kb = qkv + base + HID;
        const ushort_t* vb = qkv + base + 2 * HID;
        *(s16x8*)&K_lds[row * 136 + seg * 8] = *(const s16x8*)(kb + seg * 8);
#pragma unroll
        for (int j = 0; j < 8; ++j) {
          const int d = seg + j * 16;
          V_lds[d * 72 + row] = vb[d];
        }
      }
    }
    __syncthreads();

    // S = Q K^T
    f32x4 sa[4];
#pragma unroll
    for (int n = 0; n < 4; ++n) sa[n] = (f32x4){0.f, 0.f, 0.f, 0.f};
#pragma unroll
    for (int kd = 0; kd < 4; ++kd) {
      f16x8 kf[4];
#pragma unroll
      for (int n = 0; n < 4; ++n)
        kf[n] = *(const f16x8*)&K_lds[(n * 16 + l16) * 136 + kd * 32 + lg * 8];
#pragma unroll
      for (int n = 0; n < 4; ++n) sa[n] = MFMA16H(qf[kd], kf[n], sa[n]);
    }

    // causal mask + online softmax (rows lg*4+r, cols l16-indexed)
#pragma unroll
    for (int n = 0; n < 4; ++n) {
      const int kvg = kv0 + n * 16 + l16;
#pragma unroll
      for (int r = 0; r < 4; ++r) {
        const int qg = hb + qh * 128 + w * 16 + lg * 4 + r;
        if (kvg > qg) sa[n][r] = -1e30f;
      }
    }
    float tm[4], ts[4];
#pragma unroll
    for (int r = 0; r < 4; ++r)
      tm[r] = fmaxf(fmaxf(sa[0][r], sa[1][r]), fmaxf(sa[2][r], sa[3][r]));
#pragma unroll
    for (int x = 1; x < 16; x <<= 1)
#pragma unroll
      for (int r = 0; r < 4; ++r) tm[r] = fmaxf(tm[r], __shfl_xor(tm[r], x, 16));
#pragma unroll
    for (int r = 0; r < 4; ++r) {
      const float nm = fmaxf(mr[r], tm[r]);
      const float corr = __expf(mr[r] - nm);
      mr[r] = nm;
      sr[r] *= corr;
#pragma unroll
      for (int d = 0; d < 8; ++d) o[d][r] *= corr;
      ts[r] = 0.f;
    }
#pragma unroll
    for (int n = 0; n < 4; ++n)
#pragma unroll
      for (int r = 0; r < 4; ++r) {
        const float p = __expf(sa[n][r] - mr[r]);
        sa[n][r] = p;
        ts[r] += p;
      }
#pragma unroll
    for (int x = 1; x < 16; x <<= 1)
#pragma unroll
      for (int r = 0; r < 4; ++r) ts[r] += __shfl_xor(ts[r], x, 16);
#pragma unroll
    for (int r = 0; r < 4; ++r) sr[r] += ts[r];
#pragma unroll
    for (int n = 0; n < 4; ++n)
#pragma unroll
      for (int r = 0; r < 4; ++r)
        P_lds[(w * 16 + lg * 4 + r) * 72 + n * 16 + l16] = h2u(f2h(sa[n][r]));

    // O += P V
#pragma unroll
    for (int ks = 0; ks < 2; ++ks) {
      const f16x8 pa =
          *(const f16x8*)&P_lds[(w * 16 + l16) * 72 + ks * 32 + lg * 8];
#pragma unroll
      for (int d = 0; d < 8; ++d) {
        const f16x8 vb =
            *(const f16x8*)&V_lds[(d * 16 + l16) * 72 + ks * 32 + lg * 8];
        o[d] = MFMA16H(pa, vb, o[d]);
      }
    }
  }

  // epilogue: write directly in MFMA-tiled layout [rb][kb][lane][8]
  {
    const int rb = b * 16 + qh * 8 + w;
#pragma unroll
    for (int r = 0; r < 4; ++r) {
      const float inv = 1.0f / sr[r];
#pragma unroll
      for (int d = 0; d < 8; ++d) {
        const int kb = h * 4 + (d >> 1);
        const int lane_dst = (lg * 4 + r) | ((((d & 1) << 1) | (l16 >> 3)) << 4);
        attn_t[((size_t)(rb * 128 + kb)) * 512 + lane_dst * 8 + (l16 & 7)] =
            h2u(f2h(o[d][r] * inv));
      }
    }
  }
}

// ---------------------------------------------------------------------------
extern "C" void kernel_launch(void* const* d_in, const int* in_sizes, int n_in,
                              void* d_out, int out_size, void* d_ws,
                              size_t ws_size, hipStream_t stream) {
  const float* hidden   = (const float*)d_in[0];
  const float* c_attn_w = (const float*)d_in[1];
  const float* c_attn_b = (const float*)d_in[2];
  const float* c_proj_w = (const float*)d_in[3];
  const float* k_cache  = (const float*)d_in[4];
  const float* v_cache  = (const float*)d_in[5];
  const int* hist       = (const int*)d_in[6];
  const int* bofs       = (const int*)d_in[7];
  float* out = (float*)d_out;

  char* ws = (char*)d_ws;
  const size_t MB = 1ull << 20;
  ushort_t* w_attn_t = (ushort_t*)(ws);            // 96MB, dead after qkv GEMM
  ushort_t* wproj_t  = (ushort_t*)(ws);            // 32MB, lives after
  ushort_t* qkv_h   = (ushort_t*)(ws + 100 * MB);  // 48MB, live thru attn
  ushort_t* attn_t  = (ushort_t*)(ws + 148 * MB);  // 16MB tiled attn out
  ushort_t* x_t     = (ushort_t*)(ws + 196 * MB);  // 16MB tiled x

  // 1) tile-convert inputs for qkv GEMM
  conv_tile<<<4096, 256, 0, stream>>>(hidden, x_t, 4096, 16384);
  conv_tile<<<24576, 256, 0, stream>>>(c_attn_w, w_attn_t, 4096, 98304);
  // 2) qkv = x @ c_attn_w^T + b : 8 x 96 = 768 blocks (256x128, 8 waves)
  gemm_qkv<128><<<768, 512, 73728, stream>>>(x_t, w_attn_t, c_attn_b, qkv_h,
                                             12288);
  // 3) rope in place (q,k halves)
  rope_inplace<<<2048, 256, 0, stream>>>(qkv_h, hist);
  // 4) tile-convert proj weights (overwrites w_attn region; stream-ordered)
  conv_tile<<<8192, 256, 0, stream>>>(c_proj_w, wproj_t, 4096, 32768);
  // 5) attention -> attn_t (tiled direct), Q-half split: 512 blocks
  attn_fwd<<<512, 512, 0, stream>>>(qkv_h, k_cache, v_cache, hist, bofs,
                                    attn_t);
  // 6) out = attn @ c_proj_w^T : 16 x 32 = 512 blocks (128^2, 3/CU)
  gemm_proj<128><<<512, 256, 49152, stream>>>(attn_t, wproj_t, out, 4096);
}

// Round 13
// 406.576 us; speedup vs baseline: 1.0311x; 1.0311x over previous
//
#include <hip/hip_runtime.h>

typedef unsigned short ushort_t;
typedef float f32x4 __attribute__((ext_vector_type(4)));
typedef _Float16 f16x8 __attribute__((ext_vector_type(8)));
typedef short s16x8 __attribute__((ext_vector_type(8)));

#define NB 8
#define QL 256
#define HID 4096
#define NH 32
#define HD 128

__device__ __forceinline__ _Float16 f2h(float f) { return (_Float16)f; }
__device__ __forceinline__ ushort_t h2u(_Float16 h) {
  union { _Float16 h; ushort_t u; } x; x.h = h; return x.u;
}
__device__ __forceinline__ float u2f(ushort_t u) {
  union { _Float16 h; ushort_t u; } x; x.u = u; return (float)x.h;
}

#define MFMA16H(a, b, c) __builtin_amdgcn_mfma_f32_16x16x32_f16((a), (b), (c), 0, 0, 0)
#define AS1 __attribute__((address_space(1)))
#define AS3 __attribute__((address_space(3)))
#define VMCNT(n) asm volatile("s_waitcnt vmcnt(" #n ")" ::: "memory")
#define NOSTG

#define GLDS(srcp, dstofs)                                                    \
  __builtin_amdgcn_global_load_lds((const AS1 void*)(srcp),                   \
                                   (AS3 void*)&lds[dstofs], 16, 0, 0)

// ---------------------------------------------------------------------------
// fp32 -> fp16, MFMA-native tiling: dst[mb][kb][lane][8],
// lane = (row&15) | (seg<<4), element = src[mb*16+row][kb*32+seg*8+j].
// ---------------------------------------------------------------------------
__global__ __launch_bounds__(256)
void conv_tile(const float* __restrict__ src, ushort_t* __restrict__ dst,
               int K, int ntiles) {
  const int tile = blockIdx.x * 4 + (threadIdx.x >> 6);
  if (tile >= ntiles) return;
  const int u = threadIdx.x & 63;
  const int row = u >> 2, seg = u & 3;
  const int K32 = K >> 5;
  const int mb = tile / K32, kb = tile % K32;
  const float* sp = src + (size_t)(mb * 16 + row) * K + kb * 32 + seg * 8;
  ushort_t t[8];
#pragma unroll
  for (int j = 0; j < 8; ++j) t[j] = h2u(f2h(sp[j]));
  *(s16x8*)(dst + (size_t)tile * 512 + (((seg << 4) | row) * 8)) = *(s16x8*)t;
}

// ---------------------------------------------------------------------------
// qkv GEMM (measured-best: 180us, MfmaUtil 58%, 0 conflicts):
// BM=256 BN=128 BK=32, 8 waves (4Mx2N, wave 64x64), ring-3 LDS 72KB
// (2 blocks/CU), 1 barrier + counted vmcnt(3) per K-tile, tiled operands.
// ---------------------------------------------------------------------------
template<int NT>
__global__ __launch_bounds__(512, 4)
void gemm_qkv(const ushort_t* __restrict__ At, const ushort_t* __restrict__ Bt,
              const float* __restrict__ bias, ushort_t* __restrict__ Ch,
              int N) {
  static_assert(NT % 3 == 2 && NT >= 8, "tail assumes NT%3==2");
  extern __shared__ ushort_t lds[];  // 3 rings x (A 8192 + B 4096) elems
  const int nwg = gridDim.x, bid = blockIdx.x;
  const int wg = (bid & 7) * (nwg >> 3) + (bid >> 3);  // XCD-bijective
  const int mi = wg & 7, ni = wg >> 3;
  const int tid = threadIdx.x, w = tid >> 6, l = tid & 63;
  const int l16 = l & 15, lg = l >> 4;
  const int wm = w >> 1, wn = w & 1;

  const ushort_t* sA0 = At + ((size_t)(mi * 16 + 2 * w) * NT) * 512 + l * 8;
  const ushort_t* sA1 = At + ((size_t)(mi * 16 + 2 * w + 1) * NT) * 512 + l * 8;
  const ushort_t* sB  = Bt + ((size_t)(ni * 8 + w) * NT) * 512 + l * 8;

  int aof[4], bof[4];
#pragma unroll
  for (int mf = 0; mf < 4; ++mf) aof[mf] = (wm * 4 + mf) * 512 + l * 8;
#pragma unroll
  for (int nf = 0; nf < 4; ++nf) bof[nf] = 8192 + (wn * 4 + nf) * 512 + l * 8;

  f32x4 acc[4][4];
#pragma unroll
  for (int m = 0; m < 4; ++m)
#pragma unroll
    for (int n = 0; n < 4; ++n) acc[m][n] = (f32x4){0.f, 0.f, 0.f, 0.f};

#define STGQ(R, J)                                                            \
  do {                                                                        \
    GLDS(sA0 + (size_t)(J) * 512, (R) * 12288 + (2 * w) * 512);               \
    GLDS(sA1 + (size_t)(J) * 512, (R) * 12288 + (2 * w + 1) * 512);           \
    GLDS(sB + (size_t)(J) * 512, (R) * 12288 + 8192 + w * 512);               \
  } while (0)

#define ITERQ(R, VMW, STGCODE)                                                \
  do {                                                                        \
    VMW;                                                                      \
    __builtin_amdgcn_s_barrier();                                             \
    STGCODE;                                                                  \
    f16x8 fa[4], fb[4];                                                       \
    _Pragma("unroll") for (int mf = 0; mf < 4; ++mf)                          \
        fa[mf] = *(const f16x8*)&lds[(R) * 12288 + aof[mf]];                  \
    _Pragma("unroll") for (int nf = 0; nf < 4; ++nf)                          \
        fb[nf] = *(const f16x8*)&lds[(R) * 12288 + bof[nf]];                  \
    asm volatile("s_waitcnt lgkmcnt(0)" ::: "memory");                        \
    __builtin_amdgcn_sched_barrier(0);                                        \
    __builtin_amdgcn_s_setprio(1);                                            \
    _Pragma("unroll") for (int mf = 0; mf < 4; ++mf)                          \
    _Pragma("unroll") for (int nf = 0; nf < 4; ++nf)                          \
        acc[mf][nf] = MFMA16H(fa[mf], fb[nf], acc[mf][nf]);                   \
    __builtin_amdgcn_s_setprio(0);                                            \
  } while (0)

  STGQ(0, 0);
  STGQ(1, 1);
  for (int j = 0; j < NT - 2; j += 3) {
    ITERQ(0, VMCNT(3), STGQ(2, j + 2));
    ITERQ(1, VMCNT(3), STGQ(0, j + 3));
    ITERQ(2, VMCNT(3), STGQ(1, j + 4));
  }
  ITERQ(0, VMCNT(3), NOSTG);  // tile NT-2
  ITERQ(1, VMCNT(0), NOSTG);  // tile NT-1

  // epilogue: C/D layout col=l16, row=lg*4+rr
#pragma unroll
  for (int nf = 0; nf < 4; ++nf) {
    const int col = ni * 128 + wn * 64 + nf * 16 + l16;
    const float bi = bias[col];
#pragma unroll
    for (int mf = 0; mf < 4; ++mf) {
      const int row0 = mi * 256 + wm * 64 + mf * 16 + lg * 4;
#pragma unroll
      for (int rr = 0; rr < 4; ++rr)
        Ch[(size_t)(row0 + rr) * N + col] = h2u(f2h(acc[mf][nf][rr] + bi));
    }
  }
#undef STGQ
#undef ITERQ
}

// ---------------------------------------------------------------------------
// proj GEMM (measured-best for 2048x4096x4096): BM=BN=128, 4 waves
// (2Mx2N, wave 64x64), ring-3 LDS 48KB (3 blocks/CU), counted vmcnt(4),
// fp32 out. 512 blocks = exact fill.
// ---------------------------------------------------------------------------
template<int NT>
__global__ __launch_bounds__(256, 3)
void gemm_proj(const ushort_t* __restrict__ At, const ushort_t* __restrict__ Bt,
               float* __restrict__ Cf, int N) {
  static_assert(NT % 3 == 2 && NT >= 8, "tail assumes NT%3==2");
  extern __shared__ ushort_t lds[];  // 3 x (A 4096 + B 4096) elems = 48KB
  const int nwg = gridDim.x, bid = blockIdx.x;
  const int wg = (bid & 7) * (nwg >> 3) + (bid >> 3);
  const int mi = wg & 15, ni = wg >> 4;
  const int tid = threadIdx.x, w = tid >> 6, l = tid & 63;
  const int l16 = l & 15, lg = l >> 4;
  const int wm = w >> 1, wn = w & 1;

  const ushort_t* sA0 = At + ((size_t)(mi * 8 + 2 * w) * NT) * 512 + l * 8;
  const ushort_t* sA1 = At + ((size_t)(mi * 8 + 2 * w + 1) * NT) * 512 + l * 8;
  const ushort_t* sB0 = Bt + ((size_t)(ni * 8 + 2 * w) * NT) * 512 + l * 8;
  const ushort_t* sB1 = Bt + ((size_t)(ni * 8 + 2 * w + 1) * NT) * 512 + l * 8;

  int aof[4], bof[4];
#pragma unroll
  for (int mf = 0; mf < 4; ++mf) aof[mf] = (wm * 4 + mf) * 512 + l * 8;
#pragma unroll
  for (int nf = 0; nf < 4; ++nf) bof[nf] = 4096 + (wn * 4 + nf) * 512 + l * 8;

  f32x4 acc[4][4];
#pragma unroll
  for (int m = 0; m < 4; ++m)
#pragma unroll
    for (int n = 0; n < 4; ++n) acc[m][n] = (f32x4){0.f, 0.f, 0.f, 0.f};

#define STGP(R, J)                                                            \
  do {                                                                        \
    GLDS(sA0 + (size_t)(J) * 512, (R) * 8192 + (2 * w) * 512);                \
    GLDS(sA1 + (size_t)(J) * 512, (R) * 8192 + (2 * w + 1) * 512);            \
    GLDS(sB0 + (size_t)(J) * 512, (R) * 8192 + 4096 + (2 * w) * 512);         \
    GLDS(sB1 + (size_t)(J) * 512, (R) * 8192 + 4096 + (2 * w + 1) * 512);     \
  } while (0)

#define ITERP(R, VMW, STGCODE)                                                \
  do {                                                                        \
    VMW;                                                                      \
    __builtin_amdgcn_s_barrier();                                             \
    STGCODE;                                                                  \
    f16x8 fa[4], fb[4];                                                       \
    _Pragma("unroll") for (int mf = 0; mf < 4; ++mf)                          \
        fa[mf] = *(const f16x8*)&lds[(R) * 8192 + aof[mf]];                   \
    _Pragma("unroll") for (int nf = 0; nf < 4; ++nf)                          \
        fb[nf] = *(const f16x8*)&lds[(R) * 8192 + bof[nf]];                   \
    asm volatile("s_waitcnt lgkmcnt(0)" ::: "memory");                        \
    __builtin_amdgcn_sched_barrier(0);                                        \
    __builtin_amdgcn_s_setprio(1);                                            \
    _Pragma("unroll") for (int mf = 0; mf < 4; ++mf)                          \
    _Pragma("unroll") for (int nf = 0; nf < 4; ++nf)                          \
        acc[mf][nf] = MFMA16H(fa[mf], fb[nf], acc[mf][nf]);                   \
    __builtin_amdgcn_s_setprio(0);                                            \
  } while (0)

  STGP(0, 0);
  STGP(1, 1);
  for (int j = 0; j < NT - 2; j += 3) {
    ITERP(0, VMCNT(4), STGP(2, j + 2));
    ITERP(1, VMCNT(4), STGP(0, j + 3));
    ITERP(2, VMCNT(4), STGP(1, j + 4));
  }
  ITERP(0, VMCNT(4), NOSTG);
  ITERP(1, VMCNT(0), NOSTG);

#pragma unroll
  for (int nf = 0; nf < 4; ++nf) {
    const int col = ni * 128 + wn * 64 + nf * 16 + l16;
#pragma unroll
    for (int mf = 0; mf < 4; ++mf) {
      const int row0 = mi * 128 + wm * 64 + mf * 16 + lg * 4;
#pragma unroll
      for (int rr = 0; rr < 4; ++rr)
        Cf[(size_t)(row0 + rr) * N + col] = acc[mf][nf][rr];
    }
  }
#undef STGP
#undef ITERP
}

// ---------------------------------------------------------------------------
// RoPE in place on qkv (q cols 0..4095 with 1/sqrt(HD) folded; k cols
// 4096..8191; v untouched). Safe under graph replay: GEMM regenerates qkv.
// ---------------------------------------------------------------------------
__global__ __launch_bounds__(256)
void rope_inplace(ushort_t* __restrict__ qkv, const int* __restrict__ hist) {
  const int t = blockIdx.x;
  const int b = t >> 8, qq = t & 255;
  __shared__ float cs[64], sn[64];
  const int tid = threadIdx.x;
  if (tid < 64) {
    const float pos = (float)(hist[b] + qq);
    const float f = pos * __expf(-(float)tid * (9.210340371976184f / 64.0f));
    cs[tid] = cosf(f);
    sn[tid] = sinf(f);
  }
  __syncthreads();
  ushort_t* row = qkv + (size_t)t * 12288;
  const int h = tid >> 3;
  const int j0 = (tid & 7) * 8;
  const float qscale = 0.08838834764831845f;
  float c[8], s[8];
#pragma unroll
  for (int j = 0; j < 8; ++j) { c[j] = cs[j0 + j]; s[j] = sn[j0 + j]; }
  {
    ushort_t* p1 = row + h * HD + j0;
    ushort_t* p2 = p1 + 64;
    s16x8 a = *(s16x8*)p1, bb = *(s16x8*)p2;
    ushort_t o1[8], o2[8];
#pragma unroll
    for (int j = 0; j < 8; ++j) {
      const float x1 = u2f((ushort_t)a[j]), x2 = u2f((ushort_t)bb[j]);
      o1[j] = h2u(f2h((x1 * c[j] - x2 * s[j]) * qscale));
      o2[j] = h2u(f2h((x2 * c[j] + x1 * s[j]) * qscale));
    }
    *(s16x8*)p1 = *(s16x8*)o1;
    *(s16x8*)p2 = *(s16x8*)o2;
  }
  {
    ushort_t* p1 = row + HID + h * HD + j0;
    ushort_t* p2 = p1 + 64;
    s16x8 a = *(s16x8*)p1, bb = *(s16x8*)p2;
    ushort_t o1[8], o2[8];
#pragma unroll
    for (int j = 0; j < 8; ++j) {
      const float x1 = u2f((ushort_t)a[j]), x2 = u2f((ushort_t)bb[j]);
      o1[j] = h2u(f2h(x1 * c[j] - x2 * s[j]));
      o2[j] = h2u(f2h(x2 * c[j] + x1 * s[j]));
    }
    *(s16x8*)p1 = *(s16x8*)o1;
    *(s16x8*)p2 = *(s16x8*)o2;
  }
}

// ---------------------------------------------------------------------------
// Flash attention over paged KV (r11 structure + T14 async-STAGE split):
// 256 blocks (b,h), 8 waves x 32 Q-rows. Tile t+1's K/V global loads are
// issued into registers BEFORE tile t's compute; the reg->LDS write happens
// after the next barrier. Load latency hides under QK+softmax+PV.
// Output written directly in MFMA-tiled layout (attn_t).
// ---------------------------------------------------------------------------
__global__ __launch_bounds__(512, 2)
void attn_fwd(const ushort_t* __restrict__ qkv,
              const float* __restrict__ k_cache, const float* __restrict__ v_cache,
              const int* __restrict__ hist, const int* __restrict__ bofs,
              ushort_t* __restrict__ attn_t) {
  const int bh = blockIdx.x;
  const int b = bh >> 5, h = bh & 31;
  const int hb = hist[b];

  __shared__ ushort_t K_lds[64 * 136];
  __shared__ ushort_t V_lds[128 * 72];
  __shared__ ushort_t P_lds[256 * 72];

  const int tid = threadIdx.x;
  const int w = tid >> 6, l = tid & 63;
  const int l16 = l & 15, lg = l >> 4;

  f16x8 qf[2][4];
#pragma unroll
  for (int m = 0; m < 2; ++m) {
    const int qrow = w * 32 + m * 16 + l16;
    const ushort_t* qp = qkv + (size_t)(b * QL + qrow) * 12288 + h * HD + lg * 8;
#pragma unroll
    for (int kd = 0; kd < 4; ++kd) qf[m][kd] = *(const f16x8*)(qp + kd * 32);
  }

  f32x4 o[2][8];
  float mr[2][4], sr[2][4];
#pragma unroll
  for (int m = 0; m < 2; ++m) {
#pragma unroll
    for (int d = 0; d < 8; ++d) o[m][d] = (f32x4){0.f, 0.f, 0.f, 0.f};
#pragma unroll
    for (int r = 0; r < 4; ++r) { mr[m][r] = -1e30f; sr[m][r] = 0.f; }
  }

  const int nt = (hb + QL + 63) >> 6;
  const int srow = tid >> 4;
  const int seg = tid & 15;

  // T14: prefetch registers for the next tile's K/V rows (fp32 uniform form;
  // fp16->fp32->fp16 roundtrip is exact for fresh rows).
  float kreg[2][8], vreg[2][8];

#define LOADR(T)                                                              \
  do {                                                                        \
    _Pragma("unroll") for (int p = 0; p < 2; ++p) {                           \
      const int row_ = p * 32 + srow;                                         \
      const int kvg_ = ((T) << 6) + row_;                                     \
      if (kvg_ < hb) {                                                        \
        const int blk_ = bofs[b * 12 + (T)];                                  \
        const size_t base_ =                                                  \
            ((size_t)blk_ * 64 + (kvg_ & 63)) * HID + h * HD;                 \
        const float* kf_ = k_cache + base_;                                   \
        const float* vf_ = v_cache + base_;                                   \
        _Pragma("unroll") for (int j = 0; j < 8; ++j)                         \
            kreg[p][j] = kf_[seg * 8 + j];                                    \
        _Pragma("unroll") for (int j = 0; j < 8; ++j)                         \
            vreg[p][j] = vf_[seg + j * 16];                                   \
      } else {                                                                \
        int r2_ = kvg_ - hb;                                                  \
        if (r2_ > QL - 1) r2_ = QL - 1;                                       \
        const size_t base_ = (size_t)(b * QL + r2_) * 12288 + h * HD;         \
        const ushort_t* kb_ = qkv + base_ + HID;                              \
        const ushort_t* vb_ = qkv + base_ + 2 * HID;                          \
        _Pragma("unroll") for (int j = 0; j < 8; ++j)                         \
            kreg[p][j] = u2f(kb_[seg * 8 + j]);                               \
        _Pragma("unroll") for (int j = 0; j < 8; ++j)                         \
            vreg[p][j] = u2f(vb_[seg + j * 16]);                              \
      }                                                                       \
    }                                                                         \
  } while (0)

  LOADR(0);

  for (int t = 0; t < nt; ++t) {
    const int kv0 = t << 6;
    __syncthreads();  // all waves done reading K/V LDS from prev tile
    // write prefetched regs -> LDS
#pragma unroll
    for (int p = 0; p < 2; ++p) {
      const int row = p * 32 + srow;
      ushort_t tmp[8];
#pragma unroll
      for (int j = 0; j < 8; ++j) tmp[j] = h2u(f2h(kreg[p][j]));
      *(s16x8*)&K_lds[row * 136 + seg * 8] = *(s16x8*)tmp;
#pragma unroll
      for (int j = 0; j < 8; ++j)
        V_lds[(seg + j * 16) * 72 + row] = h2u(f2h(vreg[p][j]));
    }
    __syncthreads();
    // issue next tile's loads; latency hides under compute below
    if (t + 1 < nt) LOADR(t + 1);

    f32x4 sa[2][4];
#pragma unroll
    for (int m = 0; m < 2; ++m)
#pragma unroll
      for (int n = 0; n < 4; ++n) sa[m][n] = (f32x4){0.f, 0.f, 0.f, 0.f};
#pragma unroll
    for (int kd = 0; kd < 4; ++kd) {
      f16x8 kf[4];
#pragma unroll
      for (int n = 0; n < 4; ++n)
        kf[n] = *(const f16x8*)&K_lds[(n * 16 + l16) * 136 + kd * 32 + lg * 8];
#pragma unroll
      for (int m = 0; m < 2; ++m)
#pragma unroll
        for (int n = 0; n < 4; ++n)
          sa[m][n] = MFMA16H(qf[m][kd], kf[n], sa[m][n]);
    }

#pragma unroll
    for (int m = 0; m < 2; ++m) {
#pragma unroll
      for (int n = 0; n < 4; ++n) {
        const int kvg = kv0 + n * 16 + l16;
#pragma unroll
        for (int r = 0; r < 4; ++r) {
          const int qg = hb + w * 32 + m * 16 + lg * 4 + r;
          if (kvg > qg) sa[m][n][r] = -1e30f;
        }
      }
      float tm[4], ts[4];
#pragma unroll
      for (int r = 0; r < 4; ++r)
        tm[r] = fmaxf(fmaxf(sa[m][0][r], sa[m][1][r]),
                      fmaxf(sa[m][2][r], sa[m][3][r]));
#pragma unroll
      for (int x = 1; x < 16; x <<= 1)
#pragma unroll
        for (int r = 0; r < 4; ++r)
          tm[r] = fmaxf(tm[r], __shfl_xor(tm[r], x, 16));
#pragma unroll
      for (int r = 0; r < 4; ++r) {
        const float nm = fmaxf(mr[m][r], tm[r]);
        const float corr = __expf(mr[m][r] - nm);
        mr[m][r] = nm;
        sr[m][r] *= corr;
#pragma unroll
        for (int d = 0; d < 8; ++d) o[m][d][r] *= corr;
        ts[r] = 0.f;
      }
#pragma unroll
      for (int n = 0; n < 4; ++n)
#pragma unroll
        for (int r = 0; r < 4; ++r) {
          const float p = __expf(sa[m][n][r] - mr[m][r]);
          sa[m][n][r] = p;
          ts[r] += p;
        }
#pragma unroll
      for (int x = 1; x < 16; x <<= 1)
#pragma unroll
        for (int r = 0; r < 4; ++r) ts[r] += __shfl_xor(ts[r], x, 16);
#pragma unroll
      for (int r = 0; r < 4; ++r) sr[m][r] += ts[r];
#pragma unroll
      for (int n = 0; n < 4; ++n)
#pragma unroll
        for (int r = 0; r < 4; ++r)
          P_lds[(w * 32 + m * 16 + lg * 4 + r) * 72 + n * 16 + l16] =
              h2u(f2h(sa[m][n][r]));
    }

#pragma unroll
    for (int ks = 0; ks < 2; ++ks) {
      f16x8 pa[2];
#pragma unroll
      for (int m = 0; m < 2; ++m)
        pa[m] = *(const f16x8*)&P_lds[(w * 32 + m * 16 + l16) * 72 + ks * 32 + lg * 8];
#pragma unroll
      for (int d = 0; d < 8; ++d) {
        const f16x8 vb =
            *(const f16x8*)&V_lds[(d * 16 + l16) * 72 + ks * 32 + lg * 8];
#pragma unroll
        for (int m = 0; m < 2; ++m) o[m][d] = MFMA16H(pa[m], vb, o[m][d]);
      }
    }
  }

  // epilogue: write directly in MFMA-tiled layout [rb][kb][lane][8]
#pragma unroll
  for (int m = 0; m < 2; ++m) {
    const int rb = b * 16 + w * 2 + m;
#pragma unroll
    for (int r = 0; r < 4; ++r) {
      const float inv = 1.0f / sr[m][r];
#pragma unroll
      for (int d = 0; d < 8; ++d) {
        const int kb = h * 4 + (d >> 1);
        const int lane_dst = (lg * 4 + r) | ((((d & 1) << 1) | (l16 >> 3)) << 4);
        attn_t[((size_t)(rb * 128 + kb)) * 512 + lane_dst * 8 + (l16 & 7)] =
            h2u(f2h(o[m][d][r] * inv));
      }
    }
  }
#undef LOADR
}

// ---------------------------------------------------------------------------
extern "C" void kernel_launch(void* const* d_in, const int* in_sizes, int n_in,
                              void* d_out, int out_size, void* d_ws,
                              size_t ws_size, hipStream_t stream) {
  const float* hidden   = (const float*)d_in[0];
  const float* c_attn_w = (const float*)d_in[1];
  const float* c_attn_b = (const float*)d_in[2];
  const float* c_proj_w = (const float*)d_in[3];
  const float* k_cache  = (const float*)d_in[4];
  const float* v_cache  = (const float*)d_in[5];
  const int* hist       = (const int*)d_in[6];
  const int* bofs       = (const int*)d_in[7];
  float* out = (float*)d_out;

  char* ws = (char*)d_ws;
  const size_t MB = 1ull << 20;
  ushort_t* w_attn_t = (ushort_t*)(ws);            // 96MB, dead after qkv GEMM
  ushort_t* wproj_t  = (ushort_t*)(ws);            // 32MB, lives after
  ushort_t* qkv_h   = (ushort_t*)(ws + 100 * MB);  // 48MB, live thru attn
  ushort_t* attn_t  = (ushort_t*)(ws + 148 * MB);  // 16MB tiled attn out
  ushort_t* x_t     = (ushort_t*)(ws + 196 * MB);  // 16MB tiled x

  // 1) tile-convert inputs for qkv GEMM
  conv_tile<<<4096, 256, 0, stream>>>(hidden, x_t, 4096, 16384);
  conv_tile<<<24576, 256, 0, stream>>>(c_attn_w, w_attn_t, 4096, 98304);
  // 2) qkv = x @ c_attn_w^T + b : 8 x 96 = 768 blocks (256x128, 8 waves)
  gemm_qkv<128><<<768, 512, 73728, stream>>>(x_t, w_attn_t, c_attn_b, qkv_h,
                                             12288);
  // 3) rope in place (q,k halves)
  rope_inplace<<<2048, 256, 0, stream>>>(qkv_h, hist);
  // 4) tile-convert proj weights (overwrites w_attn region; stream-ordered)
  conv_tile<<<8192, 256, 0, stream>>>(c_proj_w, wproj_t, 4096, 32768);
  // 5) attention -> attn_t (tiled direct), 256 blocks + T14 prefetch
  attn_fwd<<<256, 512, 0, stream>>>(qkv_h, k_cache, v_cache, hist, bofs,
                                    attn_t);
  // 6) out = attn @ c_proj_w^T : 16 x 32 = 512 blocks (128^2, 3/CU)
  gemm_proj<128><<<512, 256, 49152, stream>>>(attn_t, wproj_t, out, 4096);
}